// Round 1
// baseline (550.069 us; speedup 1.0000x reference)
//
#include <hip/hip_runtime.h>
#include <math.h>

#define CC 96
#define BB 512
#define TT 512

// ---------------------------------------------------------------------------
// Kernel 0: precompute column max of transitions and E[i][j] = exp(T[i][j]-maxT[j])
// ---------------------------------------------------------------------------
__global__ __launch_bounds__(128) void crf_prep(const float* __restrict__ trans,
                                                float* __restrict__ E,
                                                float* __restrict__ maxT) {
    int j = threadIdx.x;
    if (j < CC) {
        float m = -INFINITY;
        for (int i = 0; i < CC; ++i) m = fmaxf(m, trans[i * CC + j]);
        maxT[j] = m;
        for (int i = 0; i < CC; ++i) E[i * CC + j] = __expf(trans[i * CC + j] - m);
    }
}

// ---------------------------------------------------------------------------
// Kernel 1: forward algorithm (log partition) — one block per batch.
// Thread j (j<96) owns state j: lp[j] in a register, E column j in registers.
// Per step: max-reduce lp -> p[j]=exp(lp[j]-max) in LDS -> matvec p*E ->
// lp[j] = log(sum) + max + maxT[j] + emit[t][j]
// ---------------------------------------------------------------------------
__global__ __launch_bounds__(128) void crf_forward(const float* __restrict__ emissions,
                                                   const int* __restrict__ mask,
                                                   const float* __restrict__ start_t,
                                                   const float* __restrict__ end_t,
                                                   const float* __restrict__ E,
                                                   const float* __restrict__ maxT,
                                                   float* __restrict__ log_den) {
    const int b = blockIdx.x;
    const int j = threadIdx.x;  // 0..127, active j < 96

    __shared__ __align__(16) float p[CC];
    __shared__ float red[4];

    // E column j -> registers (coalesced: fixed i, consecutive j)
    float Ecol[CC];
    if (j < CC) {
#pragma unroll
        for (int i = 0; i < CC; ++i) Ecol[i] = E[i * CC + j];
    }

    const size_t bbase = (size_t)b * TT * CC;
    float mT  = (j < CC) ? maxT[j]  : 0.f;
    float endv = (j < CC) ? end_t[j] : 0.f;

    float lpj = (j < CC) ? (start_t[j] + emissions[bbase + j]) : -INFINITY;

    // prefetch step t=1
    float em_next = (j < CC) ? emissions[bbase + CC + j] : 0.f;
    int   mk_next = mask[b * TT + 1];

    for (int t = 1; t < TT; ++t) {
        float em = em_next;
        int   mk = mk_next;
        if (t + 1 < TT) {
            em_next = (j < CC) ? emissions[bbase + (size_t)(t + 1) * CC + j] : 0.f;
            mk_next = mask[b * TT + t + 1];
        }

        // --- max over lp (2 waves) ---
        float v = (j < CC) ? lpj : -INFINITY;
#pragma unroll
        for (int off = 32; off; off >>= 1) v = fmaxf(v, __shfl_xor(v, off));
        if ((j & 63) == 0) red[j >> 6] = v;
        __syncthreads();  // (1)
        float max_lp = fmaxf(red[0], red[1]);

        // --- p = exp(lp - max) ---
        if (j < CC) p[j] = __expf(lpj - max_lp);
        __syncthreads();  // (2)

        // --- matvec: sum_i p[i] * E[i][j] ---
        float a0 = 0.f, a1 = 0.f, a2 = 0.f, a3 = 0.f;
#pragma unroll
        for (int i = 0; i < CC; i += 4) {
            float4 pv = *(const float4*)&p[i];
            a0 = fmaf(pv.x, Ecol[i + 0], a0);
            a1 = fmaf(pv.y, Ecol[i + 1], a1);
            a2 = fmaf(pv.z, Ecol[i + 2], a2);
            a3 = fmaf(pv.w, Ecol[i + 3], a3);
        }
        float sum = (a0 + a1) + (a2 + a3);

        float lp_next = __logf(sum) + max_lp + mT + em;
        if (j < CC && mk) lpj = lp_next;
        // next iteration's red-write is safe: it occurs after barrier (2)
    }

    // --- final logsumexp(lp + end) ---
    float v2 = (j < CC) ? (lpj + endv) : -INFINITY;
    float m2 = v2;
#pragma unroll
    for (int off = 32; off; off >>= 1) m2 = fmaxf(m2, __shfl_xor(m2, off));
    if ((j & 63) == 0) red[j >> 6] = m2;
    __syncthreads();
    float M = fmaxf(red[0], red[1]);
    float e = (j < CC) ? __expf(v2 - M) : 0.f;
#pragma unroll
    for (int off = 32; off; off >>= 1) e += __shfl_xor(e, off);
    if ((j & 63) == 0) red[2 + (j >> 6)] = e;
    __syncthreads();
    if (j == 0) log_den[b] = __logf(red[2] + red[3]) + M;
}

// ---------------------------------------------------------------------------
// Kernel 2: joint likelihood (numerator) — one block per batch.
// ---------------------------------------------------------------------------
__global__ __launch_bounds__(256) void crf_joint(const float* __restrict__ emissions,
                                                 const int* __restrict__ tags,
                                                 const int* __restrict__ mask,
                                                 const float* __restrict__ trans,
                                                 const float* __restrict__ start_t,
                                                 const float* __restrict__ end_t,
                                                 float* __restrict__ log_num) {
    const int b = blockIdx.x;
    const int tid = threadIdx.x;
    float s = 0.f;
    int mcount = 0;
    for (int t = tid; t < TT; t += 256) {
        int tg = tags[b * TT + t];
        float em = emissions[((size_t)b * TT + t) * CC + tg];
        int mk = mask[b * TT + t];
        mcount += mk;
        if (t == 0) {
            s += start_t[tg] + em;  // t=0 term is unmasked in the reference
        } else {
            int tp = tags[b * TT + t - 1];
            s += mk ? (trans[tp * CC + tg] + em) : 0.f;
        }
    }
    __shared__ float sred[4];
    __shared__ int mred[4];
#pragma unroll
    for (int off = 32; off; off >>= 1) {
        s += __shfl_xor(s, off);
        mcount += __shfl_xor(mcount, off);
    }
    if ((tid & 63) == 0) { sred[tid >> 6] = s; mred[tid >> 6] = mcount; }
    __syncthreads();
    if (tid == 0) {
        float tot = (sred[0] + sred[1]) + (sred[2] + sred[3]);
        int mt = (mred[0] + mred[1]) + (mred[2] + mred[3]);
        int last_tag = tags[b * TT + (mt - 1)];
        log_num[b] = tot + end_t[last_tag];
    }
}

// ---------------------------------------------------------------------------
// Kernel 3: final mean(log_den - log_num)
// ---------------------------------------------------------------------------
__global__ __launch_bounds__(512) void crf_final(const float* __restrict__ log_den,
                                                 const float* __restrict__ log_num,
                                                 float* __restrict__ out) {
    const int tid = threadIdx.x;
    float d = log_den[tid] - log_num[tid];
#pragma unroll
    for (int off = 32; off; off >>= 1) d += __shfl_xor(d, off);
    __shared__ float sred[8];
    if ((tid & 63) == 0) sred[tid >> 6] = d;
    __syncthreads();
    if (tid == 0) {
        float tot = 0.f;
        for (int w = 0; w < 8; ++w) tot += sred[w];
        out[0] = tot / (float)BB;
    }
}

extern "C" void kernel_launch(void* const* d_in, const int* in_sizes, int n_in,
                              void* d_out, int out_size, void* d_ws, size_t ws_size,
                              hipStream_t stream) {
    const float* emissions = (const float*)d_in[0];
    const int*   tags      = (const int*)d_in[1];
    const int*   mask      = (const int*)d_in[2];
    const float* trans     = (const float*)d_in[3];
    const float* start_t   = (const float*)d_in[4];
    const float* end_t     = (const float*)d_in[5];
    float* out = (float*)d_out;

    float* ws      = (float*)d_ws;
    float* E       = ws;             // 9216 floats
    float* maxT    = ws + 9216;      // 96
    float* log_den = ws + 9312;      // 512
    float* log_num = ws + 9824;      // 512

    crf_prep<<<1, 128, 0, stream>>>(trans, E, maxT);
    crf_forward<<<BB, 128, 0, stream>>>(emissions, mask, start_t, end_t, E, maxT, log_den);
    crf_joint<<<BB, 256, 0, stream>>>(emissions, tags, mask, trans, start_t, end_t, log_num);
    crf_final<<<1, 512, 0, stream>>>(log_den, log_num, out);
}

// Round 2
// 419.401 us; speedup vs baseline: 1.3116x; 1.3116x over previous
//
#include <hip/hip_runtime.h>
#include <math.h>

#define CC 96
#define BB 512
#define TT 512
#define KRENORM 8

// ---------------------------------------------------------------------------
// Kernel 0: column max of transitions and E[i][j] = exp(T[i][j]-maxT[j])
// ---------------------------------------------------------------------------
__global__ __launch_bounds__(128) void crf_prep(const float* __restrict__ trans,
                                                float* __restrict__ E,
                                                float* __restrict__ maxT) {
    int j = threadIdx.x;
    if (j < CC) {
        float m = -INFINITY;
        for (int i = 0; i < CC; ++i) m = fmaxf(m, trans[i * CC + j]);
        maxT[j] = m;
        for (int i = 0; i < CC; ++i) E[i * CC + j] = __expf(trans[i * CC + j] - m);
    }
}

// ---------------------------------------------------------------------------
// Kernel 1: forward algorithm in LINEAR probability space.
// Thread j owns state j. p kept in a register; renormalized every KRENORM
// steps (sum-norm), log-scale accumulated in double S (uniform across block).
// Per step: write p to double-buffered LDS -> ONE barrier -> matvec with
// E column in registers -> multiply by exp(maxT + emit). No per-step reduce,
// no per-step log.
// ---------------------------------------------------------------------------
__global__ __launch_bounds__(128) void crf_forward(const float* __restrict__ emissions,
                                                   const int* __restrict__ mask,
                                                   const float* __restrict__ start_t,
                                                   const float* __restrict__ end_t,
                                                   const float* __restrict__ E,
                                                   const float* __restrict__ maxT,
                                                   float* __restrict__ log_den) {
    const int b = blockIdx.x;
    const int j = threadIdx.x;  // 0..127, active j < 96
    const bool act = (j < CC);

    __shared__ __align__(16) float pbuf[2][CC];
    __shared__ float red[2];

    // E column j -> registers (coalesced across j)
    float Ecol[CC];
    if (act) {
#pragma unroll
        for (int i = 0; i < CC; ++i) Ecol[i] = E[i * CC + j];
    }

    const size_t bbase = (size_t)b * TT * CC;
    const float mT   = act ? maxT[j]  : 0.f;
    const float endv = act ? end_t[j] : 0.f;

    // --- init: lp0 = start + em0; p = exp(lp0 - max); S = max ---
    float lp0 = act ? (start_t[j] + emissions[bbase + j]) : -INFINITY;
    float m0 = lp0;
#pragma unroll
    for (int off = 32; off; off >>= 1) m0 = fmaxf(m0, __shfl_xor(m0, off));
    if ((j & 63) == 0) red[j >> 6] = m0;
    __syncthreads();
    const float M0 = fmaxf(red[0], red[1]);
    float pj = act ? __expf(lp0 - M0) : 0.f;
    double S = (double)M0;

    // prefetch step t=1
    float em_next = act ? emissions[bbase + CC + j] : 0.f;
    int   mk_next = mask[b * TT + 1];

    for (int t = 1; t < TT; ++t) {
        const float em = em_next;
        const int   mk = mk_next;
        if (t + 1 < TT) {
            em_next = act ? emissions[bbase + (size_t)(t + 1) * CC + j] : 0.f;
            mk_next = mask[b * TT + t + 1];
        }

        float* buf = pbuf[t & 1];
        if (act) buf[j] = pj;
        __syncthreads();  // single barrier per step (double-buffered p)

        // matvec: q[j] = sum_i p[i] * E[i][j]  (broadcast LDS reads)
        float a0 = 0.f, a1 = 0.f, a2 = 0.f, a3 = 0.f;
        float a4 = 0.f, a5 = 0.f, a6 = 0.f, a7 = 0.f;
#pragma unroll
        for (int i = 0; i < CC; i += 8) {
            float4 v0 = *(const float4*)&buf[i];
            float4 v1 = *(const float4*)&buf[i + 4];
            a0 = fmaf(v0.x, Ecol[i + 0], a0);
            a1 = fmaf(v0.y, Ecol[i + 1], a1);
            a2 = fmaf(v0.z, Ecol[i + 2], a2);
            a3 = fmaf(v0.w, Ecol[i + 3], a3);
            a4 = fmaf(v1.x, Ecol[i + 4], a4);
            a5 = fmaf(v1.y, Ecol[i + 5], a5);
            a6 = fmaf(v1.z, Ecol[i + 6], a6);
            a7 = fmaf(v1.w, Ecol[i + 7], a7);
        }
        const float q = ((a0 + a1) + (a2 + a3)) + ((a4 + a5) + (a6 + a7));

        const float pn = q * __expf(mT + em);
        if (act && mk) pj = pn;

        // periodic renormalization (off the common critical path)
        if ((t & (KRENORM - 1)) == 0) {
            float s = pj;
#pragma unroll
            for (int off = 32; off; off >>= 1) s += __shfl_xor(s, off);
            if ((j & 63) == 0) red[j >> 6] = s;
            __syncthreads();
            const float tot = red[0] + red[1];
            pj *= (1.0f / tot);
            S += (double)__logf(tot);
        }
    }

    // --- final: log_den = S + log(sum_j p[j] * exp(end[j])) ---
    float v2 = act ? pj * __expf(endv) : 0.f;
#pragma unroll
    for (int off = 32; off; off >>= 1) v2 += __shfl_xor(v2, off);
    if ((j & 63) == 0) red[j >> 6] = v2;
    __syncthreads();
    if (j == 0) log_den[b] = (float)(S + (double)__logf(red[0] + red[1]));
}

// ---------------------------------------------------------------------------
// Kernel 2: joint likelihood (numerator) — one block per batch.
// ---------------------------------------------------------------------------
__global__ __launch_bounds__(256) void crf_joint(const float* __restrict__ emissions,
                                                 const int* __restrict__ tags,
                                                 const int* __restrict__ mask,
                                                 const float* __restrict__ trans,
                                                 const float* __restrict__ start_t,
                                                 const float* __restrict__ end_t,
                                                 float* __restrict__ log_num) {
    const int b = blockIdx.x;
    const int tid = threadIdx.x;
    float s = 0.f;
    int mcount = 0;
    for (int t = tid; t < TT; t += 256) {
        int tg = tags[b * TT + t];
        float em = emissions[((size_t)b * TT + t) * CC + tg];
        int mk = mask[b * TT + t];
        mcount += mk;
        if (t == 0) {
            s += start_t[tg] + em;  // t=0 term unmasked in reference
        } else {
            int tp = tags[b * TT + t - 1];
            s += mk ? (trans[tp * CC + tg] + em) : 0.f;
        }
    }
    __shared__ float sred[4];
    __shared__ int mred[4];
#pragma unroll
    for (int off = 32; off; off >>= 1) {
        s += __shfl_xor(s, off);
        mcount += __shfl_xor(mcount, off);
    }
    if ((tid & 63) == 0) { sred[tid >> 6] = s; mred[tid >> 6] = mcount; }
    __syncthreads();
    if (tid == 0) {
        float tot = (sred[0] + sred[1]) + (sred[2] + sred[3]);
        int mt = (mred[0] + mred[1]) + (mred[2] + mred[3]);
        int last_tag = tags[b * TT + (mt - 1)];
        log_num[b] = tot + end_t[last_tag];
    }
}

// ---------------------------------------------------------------------------
// Kernel 3: final mean(log_den - log_num)
// ---------------------------------------------------------------------------
__global__ __launch_bounds__(512) void crf_final(const float* __restrict__ log_den,
                                                 const float* __restrict__ log_num,
                                                 float* __restrict__ out) {
    const int tid = threadIdx.x;
    float d = log_den[tid] - log_num[tid];
#pragma unroll
    for (int off = 32; off; off >>= 1) d += __shfl_xor(d, off);
    __shared__ float sred[8];
    if ((tid & 63) == 0) sred[tid >> 6] = d;
    __syncthreads();
    if (tid == 0) {
        float tot = 0.f;
        for (int w = 0; w < 8; ++w) tot += sred[w];
        out[0] = tot / (float)BB;
    }
}

extern "C" void kernel_launch(void* const* d_in, const int* in_sizes, int n_in,
                              void* d_out, int out_size, void* d_ws, size_t ws_size,
                              hipStream_t stream) {
    const float* emissions = (const float*)d_in[0];
    const int*   tags      = (const int*)d_in[1];
    const int*   mask      = (const int*)d_in[2];
    const float* trans     = (const float*)d_in[3];
    const float* start_t   = (const float*)d_in[4];
    const float* end_t     = (const float*)d_in[5];
    float* out = (float*)d_out;

    float* ws      = (float*)d_ws;
    float* E       = ws;             // 9216 floats
    float* maxT    = ws + 9216;      // 96
    float* log_den = ws + 9312;      // 512
    float* log_num = ws + 9824;      // 512

    crf_prep<<<1, 128, 0, stream>>>(trans, E, maxT);
    crf_forward<<<BB, 128, 0, stream>>>(emissions, mask, start_t, end_t, E, maxT, log_den);
    crf_joint<<<BB, 256, 0, stream>>>(emissions, tags, mask, trans, start_t, end_t, log_num);
    crf_final<<<1, 512, 0, stream>>>(log_den, log_num, out);
}